// Round 9
// baseline (546.897 us; speedup 1.0000x reference)
//
#include <hip/hip_runtime.h>

typedef __bf16 bf16;
typedef short s8v __attribute__((ext_vector_type(8)));    // 8 bf16 as shorts (4 VGPR) - MFMA A/B frag
typedef float f4v __attribute__((ext_vector_type(4)));    // MFMA C/D frag
typedef bf16 bf4v __attribute__((ext_vector_type(4)));
typedef bf16 bf8v __attribute__((ext_vector_type(8)));

#define NH 16
#define BB 8
#define QWSCALE 0.18033688011112043f  /* 0.125 * log2(e): scores in exp2 domain */

__device__ __forceinline__ void glds16(void* lds, const void* g) {
    __builtin_amdgcn_global_load_lds(
        (const __attribute__((address_space(1))) unsigned int*)g,
        (__attribute__((address_space(3))) unsigned int*)lds, 16, 0, 0);
}

// ------ fused router GEMM: C1=A@W1, C2=A@W2; M=512, N=K=1024; fp32 exact ------
// 64x32 tiles, 512 blocks (2/CU, 8 waves/CU). SIMT beats MFMA here: M=512 gives MFMA 128-tiles
// only 32 blocks (1/8 of GPU) -- round-7 measured -23us for the MFMA path.
// headed out: m=b*64+g (Lrows=64), n=h*64+d -> C[((b*16+h)*64+g)*64+d]
__global__ __launch_bounds__(256) void rgemm_k(
    const float* __restrict__ A, const float* __restrict__ W1, const float* __restrict__ W2,
    float* __restrict__ C1, float* __restrict__ C2)
{
    __shared__ float As[16][68];   // [k][m]
    __shared__ float Bs[16][36];   // [k][n] (32 cols)
    const int tid = threadIdx.x;
    const int bm = blockIdx.x;           // 0..7  (= batch b)
    int bn = blockIdx.y;                 // 0..63
    const float* W = (bn < 32) ? W1 : W2;
    float* C = (bn < 32) ? C1 : C2;
    if (bn >= 32) bn -= 32;              // 0..31
    const int h = bn >> 1;               // head
    const int dq = (bn & 1) * 32;        // d-offset within head
    const int n0 = h * 64 + dq;          // global col in W

    const int ar = tid >> 2, ac = (tid & 3) * 4;     // A loader: row, k-quad (64x16)
    const int br = tid >> 3, bc = (tid & 7) * 4;     // B loader (tid<128): k-row, n-quad (16x32)
    const int tr = (tid >> 4) * 4, tc = (tid & 15) * 2;

    float acc[4][2];
#pragma unroll
    for (int i = 0; i < 4; i++) { acc[i][0] = 0.f; acc[i][1] = 0.f; }

    for (int kt = 0; kt < 1024; kt += 16) {
        float4 av = *(const float4*)&A[(size_t)(bm * 64 + ar) * 1024 + kt + ac];
        float4 bv;
        if (tid < 128) bv = *(const float4*)&W[(size_t)(kt + br) * 1024 + n0 + bc];
        __syncthreads();
        As[ac + 0][ar] = av.x; As[ac + 1][ar] = av.y;
        As[ac + 2][ar] = av.z; As[ac + 3][ar] = av.w;
        if (tid < 128) *(float4*)&Bs[br][bc] = bv;
        __syncthreads();
#pragma unroll
        for (int k = 0; k < 16; k++) {
            float4 x = *(const float4*)&As[k][tr];
            float2 y = *(const float2*)&Bs[k][tc];
            float xv[4] = {x.x, x.y, x.z, x.w};
#pragma unroll
            for (int i = 0; i < 4; i++) {
                acc[i][0] += xv[i] * y.x;
                acc[i][1] += xv[i] * y.y;
            }
        }
    }

#pragma unroll
    for (int i = 0; i < 4; i++) {
        float2 v = make_float2(acc[i][0], acc[i][1]);
        *(float2*)&C[((size_t)(bm * NH + h) * 64 + tr + i) * 64 + dq + tc] = v;
    }
}

// ---------------- W_ep[b,h][d][e] = sum_g rq[g][d] * rk[g][e]  (fp32, headed RQ/RK) ----------------
// v3: grid 256 (bh x d-half) -- the 128-block version left half the CUs idle. Each block computes
// 32 d-rows x 64 e; identical per-output accumulation order (bitwise-same result).
__global__ __launch_bounds__(256) void wep_k(
    const float* __restrict__ RQ, const float* __restrict__ RK, float* __restrict__ WEP)
{
    const int bh = blockIdx.x >> 1;
    const int dh = blockIdx.x & 1;       // d half: rows dh*32 .. +32
    __shared__ float rqs[2048];          // [64 g][32 d]
    __shared__ float rks[4096];          // [64 g][64 e]
    const int tid = threadIdx.x;
    const float4* rk4 = (const float4*)(RK + (size_t)bh * 4096);
#pragma unroll
    for (int j = 0; j < 4; j++)
        ((float4*)rks)[tid + 256 * j] = rk4[tid + 256 * j];
#pragma unroll
    for (int j = 0; j < 2; j++) {
        int i4 = j * 256 + tid;          // 0..511
        int g = i4 >> 3, c = (i4 & 7) * 4;
        *(float4*)&rqs[g * 32 + c] =
            *(const float4*)&RQ[(size_t)bh * 4096 + g * 64 + dh * 32 + c];
    }
    __syncthreads();
    const int dd = tid >> 3;             // 0..31
    const int q = (tid & 7) * 8;         // 8 e per thread
    float acc[8];
#pragma unroll
    for (int i = 0; i < 8; i++) acc[i] = 0.f;
    for (int g = 0; g < 64; g++) {
        float a = rqs[g * 32 + dd];
        const float4* wr = (const float4*)&rks[g * 64 + q];
        float4 y0 = wr[0], y1 = wr[1];
        acc[0] += a * y0.x; acc[1] += a * y0.y; acc[2] += a * y0.z; acc[3] += a * y0.w;
        acc[4] += a * y1.x; acc[5] += a * y1.y; acc[6] += a * y1.z; acc[7] += a * y1.w;
    }
    float* out = WEP + (size_t)bh * 4096 + (dh * 32 + dd) * 64 + q;
    *(float4*)&out[0] = make_float4(acc[0], acc[1], acc[2], acc[3]);
    *(float4*)&out[4] = make_float4(acc[4], acc[5], acc[6], acc[7]);
}

// -------- WqWepT hi/lo [b][n=h*64+e][k=D] = scale * sum_d Wep[b,h][d][e] * Wq[D][h*64+d] --------
// v3: float4 inner reads (33 scalar ds_read -> 1 scalar + 8 b128 per d; b128 moves ~2x B/cy).
__global__ __launch_bounds__(256) void wqwep_k(
    const float* __restrict__ Wq, const float* __restrict__ WEP,
    bf16* __restrict__ Thi, bf16* __restrict__ Tlo)
{
    const int bh = blockIdx.x;
    const int b = bh >> 4, h = bh & 15;
    const int Dt = blockIdx.y;
    __shared__ float weps[4096];       // [d][e]
    __shared__ float wqs[128 * 68];    // [Dloc][d]; reused as uint stage [64 e][stride 132]
    const int tid = threadIdx.x;
    const float4* wsrc = (const float4*)(WEP + (size_t)bh * 4096);
#pragma unroll
    for (int it = 0; it < 4; it++)
        ((float4*)weps)[it * 256 + tid] = wsrc[it * 256 + tid];
#pragma unroll
    for (int it = 0; it < 8; it++) {
        int g = it * 256 + tid;
        int r = g >> 4, c = (g & 15) * 4;
        *(float4*)&wqs[r * 68 + c] =
            *(const float4*)&Wq[(size_t)(Dt * 128 + r) * 1024 + h * 64 + c];
    }
    __syncthreads();
    const int Dloc = tid >> 1, e0 = (tid & 1) * 32;
    float acc[32];
#pragma unroll
    for (int e = 0; e < 32; e++) acc[e] = 0.f;
    for (int d = 0; d < 64; d++) {
        float a = wqs[Dloc * 68 + d];
        const float4* wr = (const float4*)&weps[d * 64 + e0];
#pragma unroll
        for (int e4 = 0; e4 < 8; e4++) {
            float4 y = wr[e4];
            acc[e4 * 4 + 0] += a * y.x;
            acc[e4 * 4 + 1] += a * y.y;
            acc[e4 * 4 + 2] += a * y.z;
            acc[e4 * 4 + 3] += a * y.w;
        }
    }
    __syncthreads();   // all wqs/weps reads done; reuse wqs as packed hi|lo stage
    unsigned* stage = (unsigned*)wqs;  // [64 e][stride 132]
#pragma unroll
    for (int e = 0; e < 32; e++) {
        float v = acc[e] * QWSCALE;
        bf16 hv = (bf16)v;
        bf16 lv = (bf16)(v - (float)hv);
        unsigned hb = *(unsigned short*)&hv;
        unsigned lb = *(unsigned short*)&lv;
        stage[(e0 + e) * 132 + Dloc] = hb | (lb << 16);
    }
    __syncthreads();
    {
        const int e = tid >> 2, c0 = (tid & 3) * 32;
        const unsigned* src = &stage[e * 132 + c0];
        bf16 hi32[32], lo32[32];
#pragma unroll
        for (int j = 0; j < 32; j++) {
            unsigned u = src[j];
            unsigned short hb = (unsigned short)(u & 0xffff);
            unsigned short lb = (unsigned short)(u >> 16);
            hi32[j] = *(bf16*)&hb;
            lo32[j] = *(bf16*)&lb;
        }
        size_t base = ((size_t)b * 1024 + h * 64 + e) * 1024 + Dt * 128 + c0;
#pragma unroll
        for (int q8 = 0; q8 < 4; q8++) {
            *(bf8v*)&Thi[base + q8 * 8] = *(bf8v*)&hi32[q8 * 8];
            *(bf8v*)&Tlo[base + q8 * 8] = *(bf8v*)&lo32[q8 * 8];
        }
    }
}

// ---------------- split/cast fp32 -> bf16 hi (+lo) ----------------
__global__ void split_cast_k(const float* __restrict__ x, bf16* __restrict__ hi,
                             bf16* __restrict__ lo, int n4)
{
    int idx = blockIdx.x * blockDim.x + threadIdx.x;
    int stride = gridDim.x * blockDim.x;
    for (int i = idx; i < n4; i += stride) {
        float4 v = ((const float4*)x)[i];
        bf4v h;
        h[0] = (bf16)v.x; h[1] = (bf16)v.y; h[2] = (bf16)v.z; h[3] = (bf16)v.w;
        ((bf4v*)hi)[i] = h;
        if (lo) {
            bf4v l;
            l[0] = (bf16)(v.x - (float)h[0]);
            l[1] = (bf16)(v.y - (float)h[1]);
            l[2] = (bf16)(v.z - (float)h[2]);
            l[3] = (bf16)(v.w - (float)h[3]);
            ((bf4v*)lo)[i] = l;
        }
    }
}

// ------- transpose fp32 W[k][n] -> bf16 WT[n][k] (1024x1024), 3 weights in one launch -------
// z=0: Wk -> hi+lo; z=1: Wv -> hi; z=2: Wo -> hi
__global__ __launch_bounds__(256) void transw3_k(
    const float* __restrict__ W0, const float* __restrict__ W1, const float* __restrict__ W2,
    bf16* __restrict__ T0, bf16* __restrict__ T0lo, bf16* __restrict__ T1, bf16* __restrict__ T2)
{
    const float* W;
    bf16 *WT, *WTlo;
    if (blockIdx.z == 0)      { W = W0; WT = T0; WTlo = T0lo; }
    else if (blockIdx.z == 1) { W = W1; WT = T1; WTlo = nullptr; }
    else                      { W = W2; WT = T2; WTlo = nullptr; }
    __shared__ float T[64 * 68];
    const int k0 = blockIdx.x * 64, n0 = blockIdx.y * 64;
    const int tid = threadIdx.x;
#pragma unroll
    for (int it = 0; it < 4; it++) {
        int g = it * 256 + tid;
        int r = g >> 4, c = (g & 15) * 4;
        *(float4*)&T[r * 68 + c] = *(const float4*)&W[(size_t)(k0 + r) * 1024 + n0 + c];
    }
    __syncthreads();
#pragma unroll
    for (int it = 0; it < 4; it++) {
        int g = it * 256 + tid;
        int n = g >> 4, k4 = (g & 15) * 4;
        bf4v o, ol;
#pragma unroll
        for (int t = 0; t < 4; t++) {
            float v = T[(k4 + t) * 68 + n];
            o[t] = (bf16)v;
            ol[t] = (bf16)(v - (float)o[t]);
        }
        *(bf4v*)&WT[(size_t)(n0 + n) * 1024 + k0 + k4] = o;
        if (WTlo) *(bf4v*)&WTlo[(size_t)(n0 + n) * 1024 + k0 + k4] = ol;
    }
}

// ---------------- bf16 MFMA GEMM: C[m][n] = A[m][k] @ Bt[n][k]^T, M=8192, N=K=1024 ----------------
// PASSES=3: A and B both hi/lo split: acc = AhiBhi + AloBhi + AhiBlo (drop lo*lo).
// outmode 0: fp32 out[m*1024+n] + bias[n]
// outmode 1: split-headed bf16 outH/outL -- LDS-staged coalesced stores (round-8 proven)
// outmode 2: VT bf16 outH[((b*16+h)*64+d)*1024+s] -- v2: LDS-staged coalesced stores
//            (old path was 8B scatter at 2KB stride on 16.8MB)
template<int PASSES>
__global__ __launch_bounds__(256, 2) void gemm_k(
    const bf16* __restrict__ A, const bf16* __restrict__ Alo,
    const bf16* __restrict__ Bt, const bf16* __restrict__ Btlo,
    int bBatched, int outmode,
    float* __restrict__ outF, const float* __restrict__ bias,
    bf16* __restrict__ outH, bf16* __restrict__ outL)
{
    __shared__ __align__(16) char smem[(PASSES == 3) ? 65536 : 34048];
    bf16* Ah = (bf16*)smem;
    bf16* Bh = Ah + 8192;
    bf16* Al = Bh + 8192;
    bf16* Bl = Al + ((PASSES == 3) ? 8192 : 64);
    unsigned* stage = (unsigned*)smem;   // outmode-1 epilogue reuse: [64 m][stride 132] u32
    bf16* st2 = (bf16*)smem;             // outmode-2 epilogue reuse: [64 n][stride 136] bf16
    const int tid = threadIdx.x;
    const int bm = blockIdx.x, bn = blockIdx.y;
    const size_t boff = bBatched ? ((size_t)(bm >> 3) << 20) : (size_t)0;
    const bf16* Bt_b = Bt + boff;
    const bf16* Btlo_b = (PASSES == 3) ? (Btlo + boff) : nullptr;
    const int li = tid & 15;
    const int qq = (tid >> 4) & 3;
    const int wave = tid >> 6;
    const int wm0 = (wave & 1) * 64, wn0 = (wave >> 1) * 64;

    f4v acc[4][4];
    f4v zf; zf[0] = 0.f; zf[1] = 0.f; zf[2] = 0.f; zf[3] = 0.f;
#pragma unroll
    for (int mt = 0; mt < 4; mt++)
#pragma unroll
        for (int nt = 0; nt < 4; nt++) acc[mt][nt] = zf;

    for (int kt = 0; kt < 16; kt++) {
        const int col0 = kt * 64;
#pragma unroll
        for (int it = 0; it < 4; it++) {
            int g = it * 256 + tid;
            int r = g >> 3, p = g & 7;
            int gcol = col0 + ((p ^ (r & 7)) << 3);
            int ldsoff = (g & ~63) << 3;
            size_t ga = (size_t)(bm * 128 + r) * 1024 + gcol;
            size_t gb = (size_t)(bn * 128 + r) * 1024 + gcol;
            glds16(Ah + ldsoff, A + ga);
            glds16(Bh + ldsoff, Bt_b + gb);
            if (PASSES == 3) {
                glds16(Al + ldsoff, Alo + ga);
                glds16(Bl + ldsoff, Btlo_b + gb);
            }
        }
        __syncthreads();
#pragma unroll
        for (int ks = 0; ks < 2; ks++) {
            s8v af[4], alf[4], bhf[4], blf[4];
#pragma unroll
            for (int mt = 0; mt < 4; mt++) {
                int row = wm0 + mt * 16 + li;
                int off = row * 64 + (((ks * 4 + qq) ^ (li & 7)) << 3);
                af[mt] = *(const s8v*)&Ah[off];
                if (PASSES == 3) alf[mt] = *(const s8v*)&Al[off];
            }
#pragma unroll
            for (int nt = 0; nt < 4; nt++) {
                int row = wn0 + nt * 16 + li;
                int off = row * 64 + (((ks * 4 + qq) ^ (li & 7)) << 3);
                bhf[nt] = *(const s8v*)&Bh[off];
                if (PASSES == 3) blf[nt] = *(const s8v*)&Bl[off];
            }
#pragma unroll
            for (int mt = 0; mt < 4; mt++)
#pragma unroll
                for (int nt = 0; nt < 4; nt++) {
                    acc[mt][nt] = __builtin_amdgcn_mfma_f32_16x16x32_bf16(
                        af[mt], bhf[nt], acc[mt][nt], 0, 0, 0);
                    if (PASSES == 3) {
                        acc[mt][nt] = __builtin_amdgcn_mfma_f32_16x16x32_bf16(
                            alf[mt], bhf[nt], acc[mt][nt], 0, 0, 0);
                        acc[mt][nt] = __builtin_amdgcn_mfma_f32_16x16x32_bf16(
                            af[mt], blf[nt], acc[mt][nt], 0, 0, 0);
                    }
                }
        }
        __syncthreads();
    }

    // epilogue
    if (outmode == 1) {
        // two 64-row passes: pack hi|lo u32 into LDS, then coalesced re-read + 16B stores.
#pragma unroll
        for (int p = 0; p < 2; p++) {
            __syncthreads();
            if ((wave & 1) == p) {
#pragma unroll
                for (int mt = 0; mt < 4; mt++)
#pragma unroll
                    for (int nt = 0; nt < 4; nt++)
#pragma unroll
                        for (int rg = 0; rg < 4; rg++) {
                            float v = acc[mt][nt][rg];
                            bf16 hv = (bf16)v;
                            bf16 lv = (bf16)(v - (float)hv);
                            unsigned hb = *(unsigned short*)&hv;
                            unsigned lb = *(unsigned short*)&lv;
                            stage[(mt * 16 + qq * 4 + rg) * 132 + wn0 + nt * 16 + li] =
                                hb | (lb << 16);
                        }
            }
            __syncthreads();
            {
                int mloc = tid >> 2, quarter = tid & 3;
                int hh = quarter >> 1, e0 = (quarter & 1) * 32;
                int m = bm * 128 + 64 * p + mloc;
                int b = m >> 10, l = m & 1023;
                int h = bn * 2 + hh;
                const unsigned* src = &stage[mloc * 132 + hh * 64 + e0];
                bf16 hi32[32], lo32[32];
#pragma unroll
                for (int j = 0; j < 32; j++) {
                    unsigned u = src[j];
                    unsigned short hb = (unsigned short)(u & 0xffff);
                    unsigned short lb = (unsigned short)(u >> 16);
                    hi32[j] = *(bf16*)&hb;
                    lo32[j] = *(bf16*)&lb;
                }
                size_t base = ((size_t)(b * NH + h) * 1024 + l) * 64 + e0;
#pragma unroll
                for (int q8 = 0; q8 < 4; q8++) {
                    *(bf8v*)&outH[base + q8 * 8] = *(bf8v*)&hi32[q8 * 8];
                    *(bf8v*)&outL[base + q8 * 8] = *(bf8v*)&lo32[q8 * 8];
                }
            }
        }
    } else if (outmode == 2) {
        // two 64-n-row passes: stage bf16 [64 n][136 s], re-read coalesced, contiguous s stores.
        // block output rows n = bn*128 + wn0 + nt*16 + li  -> (h,d); cols s = m-local.
        const int b = bm >> 3, s0b = (bm & 7) * 128;
#pragma unroll
        for (int p = 0; p < 2; p++) {
            __syncthreads();
            if ((wave >> 1) == p) {
#pragma unroll
                for (int mt = 0; mt < 4; mt++)
#pragma unroll
                    for (int nt = 0; nt < 4; nt++) {
                        bf4v v;
                        v[0] = (bf16)acc[mt][nt][0]; v[1] = (bf16)acc[mt][nt][1];
                        v[2] = (bf16)acc[mt][nt][2]; v[3] = (bf16)acc[mt][nt][3];
                        *(bf4v*)&st2[(nt * 16 + li) * 136 + wm0 + mt * 16 + qq * 4] = v;
                    }
            }
            __syncthreads();
            {
                int nn = tid >> 2, sb = (tid & 3) * 32;
                int ng = bn * 128 + 64 * p + nn;
                int h = ng >> 6, d = ng & 63;
                const bf16* src = &st2[nn * 136 + sb];
                bf16* dst = outH + ((size_t)(b * NH + h) * 64 + d) * 1024 + s0b + sb;
#pragma unroll
                for (int q8 = 0; q8 < 4; q8++)
                    *(bf8v*)&dst[q8 * 8] = *(const bf8v*)&src[q8 * 8];
            }
        }
    } else {
#pragma unroll
        for (int mt = 0; mt < 4; mt++) {
#pragma unroll
            for (int nt = 0; nt < 4; nt++) {
                int n = bn * 128 + wn0 + nt * 16 + li;
                int m0 = bm * 128 + wm0 + mt * 16 + qq * 4;
                float bv = bias ? bias[n] : 0.f;
#pragma unroll
                for (int rg = 0; rg < 4; rg++)
                    outF[(size_t)(m0 + rg) * 1024 + n] = acc[mt][nt][rg] + bv;
            }
        }
    }
}

// ---------------- fused attention: S^T = Kp·Qw^T 3-pass, online softmax, O^T = V^T·P^T ----------------
// Output layout honors the reference's reshape quirk: O[b][h*64+d][l]  (K-dim of final GEMM = l)
// v7 (round-6 proven): 256t, Q in regs, 43008B LDS, XCD swizzle, T13 lazy-max rescale.
__global__ __launch_bounds__(256, 2) void attn_k(
    const bf16* __restrict__ QwHi, const bf16* __restrict__ QwLo,
    const bf16* __restrict__ KpHi, const bf16* __restrict__ KpLo,
    const bf16* __restrict__ VT, bf16* __restrict__ O)
{
    __shared__ __align__(16) char scratch[43008];
    bf16* Kh = (bf16*)scratch;          // [64][64] (xor-swizzled rows)
    bf16* Kl = Kh + 4096;               // [64][64]
    bf16* Vt = Kh + 8192;               // [64 d][64 s]
    bf16* Pb = Kh + 12288;              // [128 r][stride 72]
    float* Obuf = (float*)scratch;      // [64 d][stride 132] (epilogue reuse)

    const int tid = threadIdx.x;
    const int w = blockIdx.x;
    const int idx = w >> 3;
    const int l0 = (idx & 7) * 128;
    const int bh = (w & 7) + 8 * (idx >> 3);
    const int li = tid & 15;
    const int qq = (tid >> 4) & 3;
    const int wave = tid >> 6;
    const int r0w = wave * 32;

    // Q fragments hi/lo directly into registers (HW-proven value-identical to swizzled-LDS path)
    s8v qhf[2][2], qlf[2][2];           // [rt][ks]
    {
        const bf16* qh = QwHi + ((size_t)bh * 1024 + l0) * 64;
        const bf16* ql = QwLo + ((size_t)bh * 1024 + l0) * 64;
#pragma unroll
        for (int rt = 0; rt < 2; rt++) {
            int row = r0w + rt * 16 + li;
#pragma unroll
            for (int ks = 0; ks < 2; ks++) {
                int off = row * 64 + (ks * 4 + qq) * 8;
                qhf[rt][ks] = *(const s8v*)&qh[off];
                qlf[rt][ks] = *(const s8v*)&ql[off];
            }
        }
    }

    float mrun[2], lsum[2];
    mrun[0] = -__builtin_inff(); mrun[1] = -__builtin_inff();
    lsum[0] = 0.f; lsum[1] = 0.f;
    f4v accO[4][2];
    {
        f4v zf; zf[0] = 0.f; zf[1] = 0.f; zf[2] = 0.f; zf[3] = 0.f;
#pragma unroll
        for (int dt = 0; dt < 4; dt++) { accO[dt][0] = zf; accO[dt][1] = zf; }
    }

    for (int s0 = 0; s0 < 1024; s0 += 64) {
        __syncthreads();  // previous chunk's K/V/P reads done
#pragma unroll
        for (int it = 0; it < 6; it++) {
            int g = it * 256 + tid;
            int buf = g >> 9;
            int L = g & 511;
            int r = L >> 3, p = L & 7;
            int blk = (p ^ (r & 7)) << 3;
            const bf16* src;
            bf16* dstb;
            if (buf == 0)      { src = KpHi + ((size_t)bh * 1024 + s0 + r) * 64 + blk; dstb = Kh; }
            else if (buf == 1) { src = KpLo + ((size_t)bh * 1024 + s0 + r) * 64 + blk; dstb = Kl; }
            else               { src = VT + ((size_t)bh * 64 + r) * 1024 + s0 + blk;   dstb = Vt; }
            glds16(dstb + ((L & ~63) << 3), src);
        }
        __syncthreads();

        // scores: accS[ct][rt] = S^T tile; S^T rows c = ct*16+qq*4+rg, cols r = r0w+rt*16+li
        f4v accS[4][2];
        {
            f4v zf; zf[0] = 0.f; zf[1] = 0.f; zf[2] = 0.f; zf[3] = 0.f;
#pragma unroll
            for (int ct = 0; ct < 4; ct++) { accS[ct][0] = zf; accS[ct][1] = zf; }
        }
#pragma unroll
        for (int ks = 0; ks < 2; ks++) {
            s8v khf[4], klf[4];
#pragma unroll
            for (int ct = 0; ct < 4; ct++) {
                int row = ct * 16 + li;
                int off = row * 64 + (((ks * 4 + qq) ^ (li & 7)) << 3);
                khf[ct] = *(const s8v*)&Kh[off];
                klf[ct] = *(const s8v*)&Kl[off];
            }
#pragma unroll
            for (int ct = 0; ct < 4; ct++)
#pragma unroll
                for (int rt = 0; rt < 2; rt++) {
                    accS[ct][rt] = __builtin_amdgcn_mfma_f32_16x16x32_bf16(
                        khf[ct], qhf[rt][ks], accS[ct][rt], 0, 0, 0);
                    accS[ct][rt] = __builtin_amdgcn_mfma_f32_16x16x32_bf16(
                        khf[ct], qlf[rt][ks], accS[ct][rt], 0, 0, 0);
                    accS[ct][rt] = __builtin_amdgcn_mfma_f32_16x16x32_bf16(
                        klf[ct], qhf[rt][ks], accS[ct][rt], 0, 0, 0);
                }
        }

        // online softmax, lazy-max (T13): rescale only when max grows by >8 (exp2 domain).
#pragma unroll
        for (int rt = 0; rt < 2; rt++) {
            float mx = -1e30f;
#pragma unroll
            for (int ct = 0; ct < 4; ct++)
#pragma unroll
                for (int rg = 0; rg < 4; rg++) mx = fmaxf(mx, accS[ct][rt][rg]);
            mx = fmaxf(mx, __shfl_xor(mx, 16));
            mx = fmaxf(mx, __shfl_xor(mx, 32));
            if (!__all(mx - mrun[rt] <= 8.f)) {
                float mnew = fmaxf(mrun[rt], mx);
                float alpha = exp2f(mrun[rt] - mnew);
                lsum[rt] *= alpha;
                mrun[rt] = mnew;
#pragma unroll
                for (int dt = 0; dt < 4; dt++)
#pragma unroll
                    for (int rg = 0; rg < 4; rg++) accO[dt][rt][rg] *= alpha;
            }
            float ls = 0.f;
            int prow = r0w + rt * 16 + li;
#pragma unroll
            for (int ct = 0; ct < 4; ct++) {
                bf4v pv;
#pragma unroll
                for (int rg = 0; rg < 4; rg++) {
                    float p_ = exp2f(accS[ct][rt][rg] - mrun[rt]);
                    ls += p_;
                    pv[rg] = (bf16)p_;
                }
                *(bf4v*)&Pb[prow * 72 + ct * 16 + qq * 4] = pv;
            }
            ls += __shfl_xor(ls, 16);
            ls += __shfl_xor(ls, 32);
            lsum[rt] += ls;
        }
        asm volatile("" ::: "memory");  // keep P ds_writes before PV ds_reads (wave-private rows)

        // PV: accO[dt][rt] = O^T tile [d][r]
#pragma unroll
        for (int ks = 0; ks < 2; ks++) {
            s8v vf[4], pf[2];
#pragma unroll
            for (int dt = 0; dt < 4; dt++) {
                int row = dt * 16 + li;
                int off = row * 64 + (((ks * 4 + qq) ^ (li & 7)) << 3);
                vf[dt] = *(const s8v*)&Vt[off];
            }
#pragma unroll
            for (int rt = 0; rt < 2; rt++) {
                int row = r0w + rt * 16 + li;
                pf[rt] = *(const s8v*)&Pb[row * 72 + ks * 32 + qq * 8];
            }
#pragma unroll
            for (int dt = 0; dt < 4; dt++)
#pragma unroll
                for (int rt = 0; rt < 2; rt++)
                    accO[dt][rt] = __builtin_amdgcn_mfma_f32_16x16x32_bf16(
                        vf[dt], pf[rt], accO[dt][rt], 0, 0, 0);
        }
    }

    // epilogue: normalize; stage fp32 O^T in LDS, store bf16 rows.
    __syncthreads();
#pragma unroll
    for (int rt = 0; rt < 2; rt++) {
        float inv = 1.f / lsum[rt];
        int rr = r0w + rt * 16 + li;
#pragma unroll
        for (int dt = 0; dt < 4; dt++)
#pragma unroll
            for (int rg = 0; rg < 4; rg++)
                Obuf[(dt * 16 + qq * 4 + rg) * 132 + rr] = accO[dt][rt][rg] * inv;
    }
    __syncthreads();
    {
        int d = tid >> 2, c0 = (tid & 3) * 32;
        const float* src = &Obuf[d * 132 + c0];
        bf16* dst = O + ((size_t)bh * 64 + d) * 1024 + l0 + c0;
#pragma unroll
        for (int q8 = 0; q8 < 4; q8++) {
            bf8v o;
#pragma unroll
            for (int j = 0; j < 8; j++) o[j] = (bf16)src[q8 * 8 + j];
            *(bf8v*)&dst[q8 * 8] = o;
        }
    }
}

extern "C" void kernel_launch(void* const* d_in, const int* in_sizes, int n_in,
                              void* d_out, int out_size, void* d_ws, size_t ws_size,
                              hipStream_t stream) {
    const float* queries = (const float*)d_in[0];
    const float* keys    = (const float*)d_in[1];
    const float* values  = (const float*)d_in[2];
    const float* routers = (const float*)d_in[3];
    const float* Wq  = (const float*)d_in[4];
    const float* Wk  = (const float*)d_in[5];
    const float* Wv  = (const float*)d_in[6];
    const float* Wlq = (const float*)d_in[7];
    const float* Wlk = (const float*)d_in[8];
    const float* Wo  = (const float*)d_in[9];
    const float* bo  = (const float*)d_in[10];
    float* out = (float*)d_out;

    // workspace: 6 x 16.78MB big buffers + 14.7MB small = ~115.3 MB (140.5 MB proven in round 1)
    char* w = (char*)d_ws;
    const size_t BIG = 16777216;
    bf16* QwHi = (bf16*)(w);
    bf16* QwLo = (bf16*)(w + 1 * BIG);
    bf16* Thi  = (bf16*)(w + 2 * BIG);   // WqWepT hi -> reused as KpHi
    bf16* Tlo  = (bf16*)(w + 3 * BIG);   // WqWepT lo -> reused as KpLo
    bf16* actHi = (bf16*)(w + 4 * BIG);  // split activations -> reused as attn out Obf
    bf16* actLo = (bf16*)(w + 5 * BIG);  // split activations -> reused as VT
    char* w2 = w + 6 * BIG;
    const size_t SM = 2097152;
    bf16*  WkThi = (bf16*)(w2);
    bf16*  WkTlo = (bf16*)(w2 + 1 * SM);
    bf16*  WvT   = (bf16*)(w2 + 2 * SM);
    bf16*  WoT   = (bf16*)(w2 + 3 * SM);
    float* RQ    = (float*)(w2 + 4 * SM);
    float* RK    = (float*)(w2 + 5 * SM);
    float* WEP   = (float*)(w2 + 6 * SM);
    bf16* KpHi = Thi;
    bf16* KpLo = Tlo;
    bf16* VTp  = actLo;
    bf16* Obf  = actHi;

    dim3 blk(256);
    // weight prep: all three transposes in one launch
    transw3_k<<<dim3(16, 16, 3), blk, 0, stream>>>(Wk, Wv, Wo, WkThi, WkTlo, WvT, WoT);
    // router path (fp32 exact): both projections, 64x32 tiles, 512 blocks (2/CU)
    rgemm_k<<<dim3(8, 64), blk, 0, stream>>>(routers, Wlq, Wlk, RQ, RK);
    wep_k<<<dim3(2 * BB * NH), blk, 0, stream>>>(RQ, RK, WEP);
    wqwep_k<<<dim3(BB * NH, 8), blk, 0, stream>>>(Wq, WEP, Thi, Tlo);
    // Qw = queries @ (Wq Wep)[b], 3-pass split x split, split-headed out
    split_cast_k<<<1024, blk, 0, stream>>>(queries, actHi, actLo, 2097152);
    gemm_k<3><<<dim3(64, 8), blk, 0, stream>>>(actHi, actLo, Thi, Tlo, 1, 1,
                                               nullptr, nullptr, QwHi, QwLo);
    // Kp = keys @ Wk, 3-pass split x split, split-headed out (overwrites Thi/Tlo)
    split_cast_k<<<1024, blk, 0, stream>>>(keys, actHi, actLo, 2097152);
    gemm_k<3><<<dim3(64, 8), blk, 0, stream>>>(actHi, actLo, WkThi, WkTlo, 0, 1,
                                               nullptr, nullptr, KpHi, KpLo);
    // V^T = (values @ Wv)^T, plain bf16 (error negligible on V path)
    split_cast_k<<<1024, blk, 0, stream>>>(values, actHi, nullptr, 2097152);
    gemm_k<1><<<dim3(64, 8), blk, 0, stream>>>(actHi, nullptr, WvT, nullptr, 0, 2,
                                               nullptr, nullptr, VTp, nullptr);
    // fused attention -> O^T quirk layout [b][h*64+d][l]; 1D grid for XCD-locality decode
    attn_k<<<dim3(1024), blk, 0, stream>>>(QwHi, QwLo, KpHi, KpLo, VTp, Obf);
    // out = Obf @ Wo + bo (fp32 out)
    gemm_k<1><<<dim3(64, 8), blk, 0, stream>>>(Obf, nullptr, WoT, nullptr, 0, 0,
                                               out, bo, nullptr, nullptr);
}

// Round 11
// 520.016 us; speedup vs baseline: 1.0517x; 1.0517x over previous
//
#include <hip/hip_runtime.h>

typedef __bf16 bf16;
typedef short s8v __attribute__((ext_vector_type(8)));    // 8 bf16 as shorts (4 VGPR) - MFMA A/B frag
typedef float f4v __attribute__((ext_vector_type(4)));    // MFMA C/D frag
typedef bf16 bf4v __attribute__((ext_vector_type(4)));
typedef bf16 bf8v __attribute__((ext_vector_type(8)));

#define NH 16
#define BB 8
#define QWSCALE 0.18033688011112043f  /* 0.125 * log2(e): scores in exp2 domain */

__device__ __forceinline__ void glds16(void* lds, const void* g) {
    __builtin_amdgcn_global_load_lds(
        (const __attribute__((address_space(1))) unsigned int*)g,
        (__attribute__((address_space(3))) unsigned int*)lds, 16, 0, 0);
}

// ------ fused router GEMM: C1=A@W1, C2=A@W2; M=512, N=K=1024; fp32 exact ------
// 64x32 tiles, 512 blocks (2/CU, 8 waves/CU). SIMT beats MFMA here: M=512 gives MFMA 128-tiles
// only 32 blocks (1/8 of GPU) -- round-7 measured -23us for the MFMA path.
__global__ __launch_bounds__(256) void rgemm_k(
    const float* __restrict__ A, const float* __restrict__ W1, const float* __restrict__ W2,
    float* __restrict__ C1, float* __restrict__ C2)
{
    __shared__ float As[16][68];   // [k][m]
    __shared__ float Bs[16][36];   // [k][n] (32 cols)
    const int tid = threadIdx.x;
    const int bm = blockIdx.x;           // 0..7  (= batch b)
    int bn = blockIdx.y;                 // 0..63
    const float* W = (bn < 32) ? W1 : W2;
    float* C = (bn < 32) ? C1 : C2;
    if (bn >= 32) bn -= 32;              // 0..31
    const int h = bn >> 1;               // head
    const int dq = (bn & 1) * 32;        // d-offset within head
    const int n0 = h * 64 + dq;          // global col in W

    const int ar = tid >> 2, ac = (tid & 3) * 4;     // A loader: row, k-quad (64x16)
    const int br = tid >> 3, bc = (tid & 7) * 4;     // B loader (tid<128): k-row, n-quad (16x32)
    const int tr = (tid >> 4) * 4, tc = (tid & 15) * 2;

    float acc[4][2];
#pragma unroll
    for (int i = 0; i < 4; i++) { acc[i][0] = 0.f; acc[i][1] = 0.f; }

    for (int kt = 0; kt < 1024; kt += 16) {
        float4 av = *(const float4*)&A[(size_t)(bm * 64 + ar) * 1024 + kt + ac];
        float4 bv;
        if (tid < 128) bv = *(const float4*)&W[(size_t)(kt + br) * 1024 + n0 + bc];
        __syncthreads();
        As[ac + 0][ar] = av.x; As[ac + 1][ar] = av.y;
        As[ac + 2][ar] = av.z; As[ac + 3][ar] = av.w;
        if (tid < 128) *(float4*)&Bs[br][bc] = bv;
        __syncthreads();
#pragma unroll
        for (int k = 0; k < 16; k++) {
            float4 x = *(const float4*)&As[k][tr];
            float2 y = *(const float2*)&Bs[k][tc];
            float xv[4] = {x.x, x.y, x.z, x.w};
#pragma unroll
            for (int i = 0; i < 4; i++) {
                acc[i][0] += xv[i] * y.x;
                acc[i][1] += xv[i] * y.y;
            }
        }
    }

#pragma unroll
    for (int i = 0; i < 4; i++) {
        float2 v = make_float2(acc[i][0], acc[i][1]);
        *(float2*)&C[((size_t)(bm * NH + h) * 64 + tr + i) * 64 + dq + tc] = v;
    }
}

// ---------------- W_ep[b,h][d][e] = sum_g rq[g][d] * rk[g][e]  (fp32, headed RQ/RK) ----------------
// v3: grid 256 (bh x d-half) -- the 128-block version left half the CUs idle. Each block computes
// 32 d-rows x 64 e; identical per-output accumulation order (bitwise-same result).
__global__ __launch_bounds__(256) void wep_k(
    const float* __restrict__ RQ, const float* __restrict__ RK, float* __restrict__ WEP)
{
    const int bh = blockIdx.x >> 1;
    const int dh = blockIdx.x & 1;       // d half: rows dh*32 .. +32
    __shared__ float rqs[2048];          // [64 g][32 d]
    __shared__ float rks[4096];          // [64 g][64 e]
    const int tid = threadIdx.x;
    const float4* rk4 = (const float4*)(RK + (size_t)bh * 4096);
#pragma unroll
    for (int j = 0; j < 4; j++)
        ((float4*)rks)[tid + 256 * j] = rk4[tid + 256 * j];
#pragma unroll
    for (int j = 0; j < 2; j++) {
        int i4 = j * 256 + tid;          // 0..511
        int g = i4 >> 3, c = (i4 & 7) * 4;
        *(float4*)&rqs[g * 32 + c] =
            *(const float4*)&RQ[(size_t)bh * 4096 + g * 64 + dh * 32 + c];
    }
    __syncthreads();
    const int dd = tid >> 3;             // 0..31
    const int q = (tid & 7) * 8;         // 8 e per thread
    float acc[8];
#pragma unroll
    for (int i = 0; i < 8; i++) acc[i] = 0.f;
    for (int g = 0; g < 64; g++) {
        float a = rqs[g * 32 + dd];
        const float4* wr = (const float4*)&rks[g * 64 + q];
        float4 y0 = wr[0], y1 = wr[1];
        acc[0] += a * y0.x; acc[1] += a * y0.y; acc[2] += a * y0.z; acc[3] += a * y0.w;
        acc[4] += a * y1.x; acc[5] += a * y1.y; acc[6] += a * y1.z; acc[7] += a * y1.w;
    }
    float* out = WEP + (size_t)bh * 4096 + (dh * 32 + dd) * 64 + q;
    *(float4*)&out[0] = make_float4(acc[0], acc[1], acc[2], acc[3]);
    *(float4*)&out[4] = make_float4(acc[4], acc[5], acc[6], acc[7]);
}

// -------- WqWepT hi/lo [b][n=h*64+e][k=D] = scale * sum_d Wep[b,h][d][e] * Wq[D][h*64+d] --------
// v3: float4 inner reads (b128 moves ~2x B/cy vs scalar b32); same per-output FMA order.
__global__ __launch_bounds__(256) void wqwep_k(
    const float* __restrict__ Wq, const float* __restrict__ WEP,
    bf16* __restrict__ Thi, bf16* __restrict__ Tlo)
{
    const int bh = blockIdx.x;
    const int b = bh >> 4, h = bh & 15;
    const int Dt = blockIdx.y;
    __shared__ float weps[4096];       // [d][e]
    __shared__ float wqs[128 * 68];    // [Dloc][d]; reused as uint stage [64 e][stride 132]
    const int tid = threadIdx.x;
    const float4* wsrc = (const float4*)(WEP + (size_t)bh * 4096);
#pragma unroll
    for (int it = 0; it < 4; it++)
        ((float4*)weps)[it * 256 + tid] = wsrc[it * 256 + tid];
#pragma unroll
    for (int it = 0; it < 8; it++) {
        int g = it * 256 + tid;
        int r = g >> 4, c = (g & 15) * 4;
        *(float4*)&wqs[r * 68 + c] =
            *(const float4*)&Wq[(size_t)(Dt * 128 + r) * 1024 + h * 64 + c];
    }
    __syncthreads();
    const int Dloc = tid >> 1, e0 = (tid & 1) * 32;
    float acc[32];
#pragma unroll
    for (int e = 0; e < 32; e++) acc[e] = 0.f;
    for (int d = 0; d < 64; d++) {
        float a = wqs[Dloc * 68 + d];
        const float4* wr = (const float4*)&weps[d * 64 + e0];
#pragma unroll
        for (int e4 = 0; e4 < 8; e4++) {
            float4 y = wr[e4];
            acc[e4 * 4 + 0] += a * y.x;
            acc[e4 * 4 + 1] += a * y.y;
            acc[e4 * 4 + 2] += a * y.z;
            acc[e4 * 4 + 3] += a * y.w;
        }
    }
    __syncthreads();   // all wqs/weps reads done; reuse wqs as packed hi|lo stage
    unsigned* stage = (unsigned*)wqs;  // [64 e][stride 132]
#pragma unroll
    for (int e = 0; e < 32; e++) {
        float v = acc[e] * QWSCALE;
        bf16 hv = (bf16)v;
        bf16 lv = (bf16)(v - (float)hv);
        unsigned hb = *(unsigned short*)&hv;
        unsigned lb = *(unsigned short*)&lv;
        stage[(e0 + e) * 132 + Dloc] = hb | (lb << 16);
    }
    __syncthreads();
    {
        const int e = tid >> 2, c0 = (tid & 3) * 32;
        const unsigned* src = &stage[e * 132 + c0];
        bf16 hi32[32], lo32[32];
#pragma unroll
        for (int j = 0; j < 32; j++) {
            unsigned u = src[j];
            unsigned short hb = (unsigned short)(u & 0xffff);
            unsigned short lb = (unsigned short)(u >> 16);
            hi32[j] = *(bf16*)&hb;
            lo32[j] = *(bf16*)&lb;
        }
        size_t base = ((size_t)b * 1024 + h * 64 + e) * 1024 + Dt * 128 + c0;
#pragma unroll
        for (int q8 = 0; q8 < 4; q8++) {
            *(bf8v*)&Thi[base + q8 * 8] = *(bf8v*)&hi32[q8 * 8];
            *(bf8v*)&Tlo[base + q8 * 8] = *(bf8v*)&lo32[q8 * 8];
        }
    }
}

// ---------------- split/cast fp32 -> bf16 hi (+lo) ----------------
__global__ void split_cast_k(const float* __restrict__ x, bf16* __restrict__ hi,
                             bf16* __restrict__ lo, int n4)
{
    int idx = blockIdx.x * blockDim.x + threadIdx.x;
    int stride = gridDim.x * blockDim.x;
    for (int i = idx; i < n4; i += stride) {
        float4 v = ((const float4*)x)[i];
        bf4v h;
        h[0] = (bf16)v.x; h[1] = (bf16)v.y; h[2] = (bf16)v.z; h[3] = (bf16)v.w;
        ((bf4v*)hi)[i] = h;
        if (lo) {
            bf4v l;
            l[0] = (bf16)(v.x - (float)h[0]);
            l[1] = (bf16)(v.y - (float)h[1]);
            l[2] = (bf16)(v.z - (float)h[2]);
            l[3] = (bf16)(v.w - (float)h[3]);
            ((bf4v*)lo)[i] = l;
        }
    }
}

// ------- transpose fp32 W[k][n] -> bf16 WT[n][k] (1024x1024), 3 weights in one launch -------
// z=0: Wk -> hi+lo; z=1: Wv -> hi; z=2: Wo -> hi
__global__ __launch_bounds__(256) void transw3_k(
    const float* __restrict__ W0, const float* __restrict__ W1, const float* __restrict__ W2,
    bf16* __restrict__ T0, bf16* __restrict__ T0lo, bf16* __restrict__ T1, bf16* __restrict__ T2)
{
    const float* W;
    bf16 *WT, *WTlo;
    if (blockIdx.z == 0)      { W = W0; WT = T0; WTlo = T0lo; }
    else if (blockIdx.z == 1) { W = W1; WT = T1; WTlo = nullptr; }
    else                      { W = W2; WT = T2; WTlo = nullptr; }
    __shared__ float T[64 * 68];
    const int k0 = blockIdx.x * 64, n0 = blockIdx.y * 64;
    const int tid = threadIdx.x;
#pragma unroll
    for (int it = 0; it < 4; it++) {
        int g = it * 256 + tid;
        int r = g >> 4, c = (g & 15) * 4;
        *(float4*)&T[r * 68 + c] = *(const float4*)&W[(size_t)(k0 + r) * 1024 + n0 + c];
    }
    __syncthreads();
#pragma unroll
    for (int it = 0; it < 4; it++) {
        int g = it * 256 + tid;
        int n = g >> 4, k4 = (g & 15) * 4;
        bf4v o, ol;
#pragma unroll
        for (int t = 0; t < 4; t++) {
            float v = T[(k4 + t) * 68 + n];
            o[t] = (bf16)v;
            ol[t] = (bf16)(v - (float)o[t]);
        }
        *(bf4v*)&WT[(size_t)(n0 + n) * 1024 + k0 + k4] = o;
        if (WTlo) *(bf4v*)&WTlo[(size_t)(n0 + n) * 1024 + k0 + k4] = ol;
    }
}

// ---------------- bf16 MFMA GEMM: C[m][n] = A[m][k] @ Bt[n][k]^T, M=8192, N=K=1024 ----------------
// PASSES=3: A and B both hi/lo split: acc = AhiBhi + AloBhi + AhiBlo (drop lo*lo).
// outmode 0: fp32 out[m*1024+n] + bias[n]
// outmode 1: split-headed bf16 outH/outL -- LDS-staged coalesced stores (round-8 proven)
// outmode 2: VT bf16 outH[((b*16+h)*64+d)*1024+s] (scatter stores; round-9's staged version
//            regressed -- scatters here are fire-and-forget and not BW-bound)
template<int PASSES>
__global__ __launch_bounds__(256, 2) void gemm_k(
    const bf16* __restrict__ A, const bf16* __restrict__ Alo,
    const bf16* __restrict__ Bt, const bf16* __restrict__ Btlo,
    int bBatched, int outmode,
    float* __restrict__ outF, const float* __restrict__ bias,
    bf16* __restrict__ outH, bf16* __restrict__ outL)
{
    __shared__ __align__(16) char smem[(PASSES == 3) ? 65536 : 34048];
    bf16* Ah = (bf16*)smem;
    bf16* Bh = Ah + 8192;
    bf16* Al = Bh + 8192;
    bf16* Bl = Al + ((PASSES == 3) ? 8192 : 64);
    unsigned* stage = (unsigned*)smem;   // outmode-1 epilogue reuse: [64 m][stride 132] u32
    const int tid = threadIdx.x;
    const int bm = blockIdx.x, bn = blockIdx.y;
    const size_t boff = bBatched ? ((size_t)(bm >> 3) << 20) : (size_t)0;
    const bf16* Bt_b = Bt + boff;
    const bf16* Btlo_b = (PASSES == 3) ? (Btlo + boff) : nullptr;
    const int li = tid & 15;
    const int qq = (tid >> 4) & 3;
    const int wave = tid >> 6;
    const int wm0 = (wave & 1) * 64, wn0 = (wave >> 1) * 64;

    f4v acc[4][4];
    f4v zf; zf[0] = 0.f; zf[1] = 0.f; zf[2] = 0.f; zf[3] = 0.f;
#pragma unroll
    for (int mt = 0; mt < 4; mt++)
#pragma unroll
        for (int nt = 0; nt < 4; nt++) acc[mt][nt] = zf;

    for (int kt = 0; kt < 16; kt++) {
        const int col0 = kt * 64;
#pragma unroll
        for (int it = 0; it < 4; it++) {
            int g = it * 256 + tid;
            int r = g >> 3, p = g & 7;
            int gcol = col0 + ((p ^ (r & 7)) << 3);
            int ldsoff = (g & ~63) << 3;
            size_t ga = (size_t)(bm * 128 + r) * 1024 + gcol;
            size_t gb = (size_t)(bn * 128 + r) * 1024 + gcol;
            glds16(Ah + ldsoff, A + ga);
            glds16(Bh + ldsoff, Bt_b + gb);
            if (PASSES == 3) {
                glds16(Al + ldsoff, Alo + ga);
                glds16(Bl + ldsoff, Btlo_b + gb);
            }
        }
        __syncthreads();
#pragma unroll
        for (int ks = 0; ks < 2; ks++) {
            s8v af[4], alf[4], bhf[4], blf[4];
#pragma unroll
            for (int mt = 0; mt < 4; mt++) {
                int row = wm0 + mt * 16 + li;
                int off = row * 64 + (((ks * 4 + qq) ^ (li & 7)) << 3);
                af[mt] = *(const s8v*)&Ah[off];
                if (PASSES == 3) alf[mt] = *(const s8v*)&Al[off];
            }
#pragma unroll
            for (int nt = 0; nt < 4; nt++) {
                int row = wn0 + nt * 16 + li;
                int off = row * 64 + (((ks * 4 + qq) ^ (li & 7)) << 3);
                bhf[nt] = *(const s8v*)&Bh[off];
                if (PASSES == 3) blf[nt] = *(const s8v*)&Bl[off];
            }
#pragma unroll
            for (int mt = 0; mt < 4; mt++)
#pragma unroll
                for (int nt = 0; nt < 4; nt++) {
                    acc[mt][nt] = __builtin_amdgcn_mfma_f32_16x16x32_bf16(
                        af[mt], bhf[nt], acc[mt][nt], 0, 0, 0);
                    if (PASSES == 3) {
                        acc[mt][nt] = __builtin_amdgcn_mfma_f32_16x16x32_bf16(
                            alf[mt], bhf[nt], acc[mt][nt], 0, 0, 0);
                        acc[mt][nt] = __builtin_amdgcn_mfma_f32_16x16x32_bf16(
                            af[mt], blf[nt], acc[mt][nt], 0, 0, 0);
                    }
                }
        }
        __syncthreads();
    }

    // epilogue
    if (outmode == 1) {
        // two 64-row passes: pack hi|lo u32 into LDS, then coalesced re-read + 16B stores.
#pragma unroll
        for (int p = 0; p < 2; p++) {
            __syncthreads();
            if ((wave & 1) == p) {
#pragma unroll
                for (int mt = 0; mt < 4; mt++)
#pragma unroll
                    for (int nt = 0; nt < 4; nt++)
#pragma unroll
                        for (int rg = 0; rg < 4; rg++) {
                            float v = acc[mt][nt][rg];
                            bf16 hv = (bf16)v;
                            bf16 lv = (bf16)(v - (float)hv);
                            unsigned hb = *(unsigned short*)&hv;
                            unsigned lb = *(unsigned short*)&lv;
                            stage[(mt * 16 + qq * 4 + rg) * 132 + wn0 + nt * 16 + li] =
                                hb | (lb << 16);
                        }
            }
            __syncthreads();
            {
                int mloc = tid >> 2, quarter = tid & 3;
                int hh = quarter >> 1, e0 = (quarter & 1) * 32;
                int m = bm * 128 + 64 * p + mloc;
                int b = m >> 10, l = m & 1023;
                int h = bn * 2 + hh;
                const unsigned* src = &stage[mloc * 132 + hh * 64 + e0];
                bf16 hi32[32], lo32[32];
#pragma unroll
                for (int j = 0; j < 32; j++) {
                    unsigned u = src[j];
                    unsigned short hb = (unsigned short)(u & 0xffff);
                    unsigned short lb = (unsigned short)(u >> 16);
                    hi32[j] = *(bf16*)&hb;
                    lo32[j] = *(bf16*)&lb;
                }
                size_t base = ((size_t)(b * NH + h) * 1024 + l) * 64 + e0;
#pragma unroll
                for (int q8 = 0; q8 < 4; q8++) {
                    *(bf8v*)&outH[base + q8 * 8] = *(bf8v*)&hi32[q8 * 8];
                    *(bf8v*)&outL[base + q8 * 8] = *(bf8v*)&lo32[q8 * 8];
                }
            }
        }
    } else {
#pragma unroll
        for (int mt = 0; mt < 4; mt++) {
#pragma unroll
            for (int nt = 0; nt < 4; nt++) {
                int n = bn * 128 + wn0 + nt * 16 + li;
                int m0 = bm * 128 + wm0 + mt * 16 + qq * 4;
                if (outmode == 0) {
                    float bv = bias ? bias[n] : 0.f;
#pragma unroll
                    for (int rg = 0; rg < 4; rg++)
                        outF[(size_t)(m0 + rg) * 1024 + n] = acc[mt][nt][rg] + bv;
                } else {
                    int b = m0 >> 10, s = m0 & 1023;
                    int h = n >> 6, d = n & 63;
                    bf4v v;
                    v[0] = (bf16)acc[mt][nt][0]; v[1] = (bf16)acc[mt][nt][1];
                    v[2] = (bf16)acc[mt][nt][2]; v[3] = (bf16)acc[mt][nt][3];
                    *(bf4v*)&outH[((size_t)(b * NH + h) * 64 + d) * 1024 + s] = v;
                }
            }
        }
    }
}

// ---------------- fused attention: S^T = Kp·Qw^T 3-pass, online softmax, O^T = V^T·P^T ----------------
// Output layout honors the reference's reshape quirk: O[b][h*64+d][l]  (K-dim of final GEMM = l)
// v7 (round-6 proven): 256t, Q in regs, 43008B LDS, XCD swizzle, T13 lazy-max rescale.
__global__ __launch_bounds__(256, 2) void attn_k(
    const bf16* __restrict__ QwHi, const bf16* __restrict__ QwLo,
    const bf16* __restrict__ KpHi, const bf16* __restrict__ KpLo,
    const bf16* __restrict__ VT, bf16* __restrict__ O)
{
    __shared__ __align__(16) char scratch[43008];
    bf16* Kh = (bf16*)scratch;          // [64][64] (xor-swizzled rows)
    bf16* Kl = Kh + 4096;               // [64][64]
    bf16* Vt = Kh + 8192;               // [64 d][64 s]
    bf16* Pb = Kh + 12288;              // [128 r][stride 72]
    float* Obuf = (float*)scratch;      // [64 d][stride 132] (epilogue reuse)

    const int tid = threadIdx.x;
    const int w = blockIdx.x;
    const int idx = w >> 3;
    const int l0 = (idx & 7) * 128;
    const int bh = (w & 7) + 8 * (idx >> 3);
    const int li = tid & 15;
    const int qq = (tid >> 4) & 3;
    const int wave = tid >> 6;
    const int r0w = wave * 32;

    // Q fragments hi/lo directly into registers (HW-proven value-identical to swizzled-LDS path)
    s8v qhf[2][2], qlf[2][2];           // [rt][ks]
    {
        const bf16* qh = QwHi + ((size_t)bh * 1024 + l0) * 64;
        const bf16* ql = QwLo + ((size_t)bh * 1024 + l0) * 64;
#pragma unroll
        for (int rt = 0; rt < 2; rt++) {
            int row = r0w + rt * 16 + li;
#pragma unroll
            for (int ks = 0; ks < 2; ks++) {
                int off = row * 64 + (ks * 4 + qq) * 8;
                qhf[rt][ks] = *(const s8v*)&qh[off];
                qlf[rt][ks] = *(const s8v*)&ql[off];
            }
        }
    }

    float mrun[2], lsum[2];
    mrun[0] = -__builtin_inff(); mrun[1] = -__builtin_inff();
    lsum[0] = 0.f; lsum[1] = 0.f;
    f4v accO[4][2];
    {
        f4v zf; zf[0] = 0.f; zf[1] = 0.f; zf[2] = 0.f; zf[3] = 0.f;
#pragma unroll
        for (int dt = 0; dt < 4; dt++) { accO[dt][0] = zf; accO[dt][1] = zf; }
    }

    for (int s0 = 0; s0 < 1024; s0 += 64) {
        __syncthreads();  // previous chunk's K/V/P reads done
#pragma unroll
        for (int it = 0; it < 6; it++) {
            int g = it * 256 + tid;
            int buf = g >> 9;
            int L = g & 511;
            int r = L >> 3, p = L & 7;
            int blk = (p ^ (r & 7)) << 3;
            const bf16* src;
            bf16* dstb;
            if (buf == 0)      { src = KpHi + ((size_t)bh * 1024 + s0 + r) * 64 + blk; dstb = Kh; }
            else if (buf == 1) { src = KpLo + ((size_t)bh * 1024 + s0 + r) * 64 + blk; dstb = Kl; }
            else               { src = VT + ((size_t)bh * 64 + r) * 1024 + s0 + blk;   dstb = Vt; }
            glds16(dstb + ((L & ~63) << 3), src);
        }
        __syncthreads();

        // scores: accS[ct][rt] = S^T tile; S^T rows c = ct*16+qq*4+rg, cols r = r0w+rt*16+li
        f4v accS[4][2];
        {
            f4v zf; zf[0] = 0.f; zf[1] = 0.f; zf[2] = 0.f; zf[3] = 0.f;
#pragma unroll
            for (int ct = 0; ct < 4; ct++) { accS[ct][0] = zf; accS[ct][1] = zf; }
        }
#pragma unroll
        for (int ks = 0; ks < 2; ks++) {
            s8v khf[4], klf[4];
#pragma unroll
            for (int ct = 0; ct < 4; ct++) {
                int row = ct * 16 + li;
                int off = row * 64 + (((ks * 4 + qq) ^ (li & 7)) << 3);
                khf[ct] = *(const s8v*)&Kh[off];
                klf[ct] = *(const s8v*)&Kl[off];
            }
#pragma unroll
            for (int ct = 0; ct < 4; ct++)
#pragma unroll
                for (int rt = 0; rt < 2; rt++) {
                    accS[ct][rt] = __builtin_amdgcn_mfma_f32_16x16x32_bf16(
                        khf[ct], qhf[rt][ks], accS[ct][rt], 0, 0, 0);
                    accS[ct][rt] = __builtin_amdgcn_mfma_f32_16x16x32_bf16(
                        khf[ct], qlf[rt][ks], accS[ct][rt], 0, 0, 0);
                    accS[ct][rt] = __builtin_amdgcn_mfma_f32_16x16x32_bf16(
                        klf[ct], qhf[rt][ks], accS[ct][rt], 0, 0, 0);
                }
        }

        // online softmax, lazy-max (T13): rescale only when max grows by >8 (exp2 domain).
#pragma unroll
        for (int rt = 0; rt < 2; rt++) {
            float mx = -1e30f;
#pragma unroll
            for (int ct = 0; ct < 4; ct++)
#pragma unroll
                for (int rg = 0; rg < 4; rg++) mx = fmaxf(mx, accS[ct][rt][rg]);
            mx = fmaxf(mx, __shfl_xor(mx, 16));
            mx = fmaxf(mx, __shfl_xor(mx, 32));
            if (!__all(mx - mrun[rt] <= 8.f)) {
                float mnew = fmaxf(mrun[rt], mx);
                float alpha = exp2f(mrun[rt] - mnew);
                lsum[rt] *= alpha;
                mrun[rt] = mnew;
#pragma unroll
                for (int dt = 0; dt < 4; dt++)
#pragma unroll
                    for (int rg = 0; rg < 4; rg++) accO[dt][rt][rg] *= alpha;
            }
            float ls = 0.f;
            int prow = r0w + rt * 16 + li;
#pragma unroll
            for (int ct = 0; ct < 4; ct++) {
                bf4v pv;
#pragma unroll
                for (int rg = 0; rg < 4; rg++) {
                    float p_ = exp2f(accS[ct][rt][rg] - mrun[rt]);
                    ls += p_;
                    pv[rg] = (bf16)p_;
                }
                *(bf4v*)&Pb[prow * 72 + ct * 16 + qq * 4] = pv;
            }
            ls += __shfl_xor(ls, 16);
            ls += __shfl_xor(ls, 32);
            lsum[rt] += ls;
        }
        asm volatile("" ::: "memory");  // keep P ds_writes before PV ds_reads (wave-private rows)

        // PV: accO[dt][rt] = O^T tile [d][r]
#pragma unroll
        for (int ks = 0; ks < 2; ks++) {
            s8v vf[4], pf[2];
#pragma unroll
            for (int dt = 0; dt < 4; dt++) {
                int row = dt * 16 + li;
                int off = row * 64 + (((ks * 4 + qq) ^ (li & 7)) << 3);
                vf[dt] = *(const s8v*)&Vt[off];
            }
#pragma unroll
            for (int rt = 0; rt < 2; rt++) {
                int row = r0w + rt * 16 + li;
                pf[rt] = *(const s8v*)&Pb[row * 72 + ks * 32 + qq * 8];
            }
#pragma unroll
            for (int dt = 0; dt < 4; dt++)
#pragma unroll
                for (int rt = 0; rt < 2; rt++)
                    accO[dt][rt] = __builtin_amdgcn_mfma_f32_16x16x32_bf16(
                        vf[dt], pf[rt], accO[dt][rt], 0, 0, 0);
        }
    }

    // epilogue: normalize; stage fp32 O^T in LDS, store bf16 rows.
    __syncthreads();
#pragma unroll
    for (int rt = 0; rt < 2; rt++) {
        float inv = 1.f / lsum[rt];
        int rr = r0w + rt * 16 + li;
#pragma unroll
        for (int dt = 0; dt < 4; dt++)
#pragma unroll
            for (int rg = 0; rg < 4; rg++)
                Obuf[(dt * 16 + qq * 4 + rg) * 132 + rr] = accO[dt][rt][rg] * inv;
    }
    __syncthreads();
    {
        int d = tid >> 2, c0 = (tid & 3) * 32;
        const float* src = &Obuf[d * 132 + c0];
        bf16* dst = O + ((size_t)bh * 64 + d) * 1024 + l0 + c0;
#pragma unroll
        for (int q8 = 0; q8 < 4; q8++) {
            bf8v o;
#pragma unroll
            for (int j = 0; j < 8; j++) o[j] = (bf16)src[q8 * 8 + j];
            *(bf8v*)&dst[q8 * 8] = o;
        }
    }
}

extern "C" void kernel_launch(void* const* d_in, const int* in_sizes, int n_in,
                              void* d_out, int out_size, void* d_ws, size_t ws_size,
                              hipStream_t stream) {
    const float* queries = (const float*)d_in[0];
    const float* keys    = (const float*)d_in[1];
    const float* values  = (const float*)d_in[2];
    const float* routers = (const float*)d_in[3];
    const float* Wq  = (const float*)d_in[4];
    const float* Wk  = (const float*)d_in[5];
    const float* Wv  = (const float*)d_in[6];
    const float* Wlq = (const float*)d_in[7];
    const float* Wlk = (const float*)d_in[8];
    const float* Wo  = (const float*)d_in[9];
    const float* bo  = (const float*)d_in[10];
    float* out = (float*)d_out;

    // workspace: 6 x 16.78MB big buffers + 14.7MB small = ~115.3 MB (140.5 MB proven in round 1)
    char* w = (char*)d_ws;
    const size_t BIG = 16777216;
    bf16* QwHi = (bf16*)(w);
    bf16* QwLo = (bf16*)(w + 1 * BIG);
    bf16* Thi  = (bf16*)(w + 2 * BIG);   // WqWepT hi -> reused as KpHi
    bf16* Tlo  = (bf16*)(w + 3 * BIG);   // WqWepT lo -> reused as KpLo
    bf16* actHi = (bf16*)(w + 4 * BIG);  // split activations -> reused as attn out Obf
    bf16* actLo = (bf16*)(w + 5 * BIG);  // split activations -> reused as VT
    char* w2 = w + 6 * BIG;
    const size_t SM = 2097152;
    bf16*  WkThi = (bf16*)(w2);
    bf16*  WkTlo = (bf16*)(w2 + 1 * SM);
    bf16*  WvT   = (bf16*)(w2 + 2 * SM);
    bf16*  WoT   = (bf16*)(w2 + 3 * SM);
    float* RQ    = (float*)(w2 + 4 * SM);
    float* RK    = (float*)(w2 + 5 * SM);
    float* WEP   = (float*)(w2 + 6 * SM);
    bf16* KpHi = Thi;
    bf16* KpLo = Tlo;
    bf16* VTp  = actLo;
    bf16* Obf  = actHi;

    dim3 blk(256);
    // weight prep: all three transposes in one launch
    transw3_k<<<dim3(16, 16, 3), blk, 0, stream>>>(Wk, Wv, Wo, WkThi, WkTlo, WvT, WoT);
    // router path (fp32 exact): both projections, 64x32 tiles, 512 blocks (2/CU)
    rgemm_k<<<dim3(8, 64), blk, 0, stream>>>(routers, Wlq, Wlk, RQ, RK);
    wep_k<<<dim3(2 * BB * NH), blk, 0, stream>>>(RQ, RK, WEP);
    wqwep_k<<<dim3(BB * NH, 8), blk, 0, stream>>>(Wq, WEP, Thi, Tlo);
    // Qw = queries @ (Wq Wep)[b], 3-pass split x split, split-headed out
    split_cast_k<<<1024, blk, 0, stream>>>(queries, actHi, actLo, 2097152);
    gemm_k<3><<<dim3(64, 8), blk, 0, stream>>>(actHi, actLo, Thi, Tlo, 1, 1,
                                               nullptr, nullptr, QwHi, QwLo);
    // Kp = keys @ Wk, 3-pass split x split, split-headed out (overwrites Thi/Tlo)
    split_cast_k<<<1024, blk, 0, stream>>>(keys, actHi, actLo, 2097152);
    gemm_k<3><<<dim3(64, 8), blk, 0, stream>>>(actHi, actLo, WkThi, WkTlo, 0, 1,
                                               nullptr, nullptr, KpHi, KpLo);
    // V^T = (values @ Wv)^T, plain bf16 (error negligible on V path)
    split_cast_k<<<1024, blk, 0, stream>>>(values, actHi, nullptr, 2097152);
    gemm_k<1><<<dim3(64, 8), blk, 0, stream>>>(actHi, nullptr, WvT, nullptr, 0, 2,
                                               nullptr, nullptr, VTp, nullptr);
    // fused attention -> O^T quirk layout [b][h*64+d][l]; 1D grid for XCD-locality decode
    attn_k<<<dim3(1024), blk, 0, stream>>>(QwHi, QwLo, KpHi, KpLo, VTp, Obf);
    // out = Obf @ Wo + bo (fp32 out)
    gemm_k<1><<<dim3(64, 8), blk, 0, stream>>>(Obf, nullptr, WoT, nullptr, 0, 0,
                                               out, bo, nullptr, nullptr);
}